// Round 13
// baseline (9274.879 us; speedup 1.0000x reference)
//
#include <hip/hip_runtime.h>
#include <math.h>

// NeuroRNN: I = 0.8 I + 0.2 (Wrec r + Win x_t); r = 0.9 r + 0.1 tanh(I); out = Wout r
// B=32, T=2048, IN=256, H=1024, OUT=128 (all fp32)
//
// R13 = R12 lean skeleton + TWO-STREAM latency hiding (R11 retry, diagnosed):
// 16 groups x 2 batches. WG (P=blk&7, jb=blk>>3) serves gA=P and gB=P+8 with
// SHARED static bf16 Wrec/Win/Wout A-frags in VGPRs. Per outer iter: phase A
// then phase B; each stream's publish->poll separation is one full other-phase
// (>= MALL visibility latency) so polls hit on the first try. One barrier per
// phase: stream S's stage(t+1) is ordered against its MFMA(t) reads by the
// OTHER stream's barrier (program order), and r_lds slots are per-stream.
// Exchange protocol unchanged (R7-R12 proven): self-validating bf16 r with
// dword-LSB step tag, sc0 sc1 MALL accesses, fire-and-forget publish.

#define T_STEPS 2048
#define IN_SZ 256
#define H_SZ 1024
#define OUT_SZ 128
#define WGS 256
#define NWG 256
#define PB_WORDS 16384                 // per dbuf half: 16 groups x 1024 dwords
#define WS_WORDS (2 * PB_WORDS)

typedef unsigned int u32;
typedef u32 u32x2 __attribute__((ext_vector_type(2)));
typedef u32 u32x4 __attribute__((ext_vector_type(4)));
typedef float f32x4 __attribute__((ext_vector_type(4)));
typedef short s16x8 __attribute__((ext_vector_type(8)));

// init: tag bit = 1 (expected tag for "step -1"), bf16 halves ~= 0
__global__ void nrnn_init_ws(u32* __restrict__ ws) {
  const int i = blockIdx.x * blockDim.x + threadIdx.x;
  if (i < WS_WORDS) ws[i] = 0x00000001u;
}

__device__ __forceinline__ u32 bf16r(float v) {  // round-to-nearest-even bf16
  const u32 b = __float_as_uint(v);
  return (b + 0x7FFFu + ((b >> 16) & 1u)) >> 16;
}
__device__ __forceinline__ float tanh_fast(float v) {
  const float cx = fminf(fmaxf(v, -15.f), 15.f);
  const float e = __expf(2.f * cx);
  return (e - 1.f) * __builtin_amdgcn_rcpf(e + 1.f);
}

// One stream-phase. G=group, SLOT=LDS slot, SW=this stream's sweep regs,
// SWN=next sweep regs to issue (group NG, dbuf NB), IST/RL=I and r state,
// XF=this stream's packed-x frags (consumed, then refilled for t+1).
#define PHASE(G, SLOT, t, SW, SWN, NG, NB, IST, RL, XF)                       \
  do {                                                                        \
    const u32 etag_ = (((u32)((t) - 1)) >> 1) & 1u;                           \
    const u32* sp_ = pbuf + (size_t)(((t) + 1) & 1) * PB_WORDS                \
                     + (size_t)(G) * 1024 + 4 * tid;                          \
    asm volatile("s_waitcnt vmcnt(0)" : "+v"(SW) :: "memory");                \
    for (;;) {                                                                \
      const u32 bad_ = (SW[0] ^ etag_) | (SW[1] ^ etag_) |                    \
                       (SW[2] ^ etag_) | (SW[3] ^ etag_);                     \
      if (!__any(bad_ & 1u)) break;                                           \
      asm volatile("global_load_dwordx4 %0, %1, off sc0 sc1\n\t"              \
                   "s_waitcnt vmcnt(0)"                                       \
                   : "=&v"(SW) : "v"(sp_) : "memory");                        \
    }                                                                         \
    *(u32x4*)(&r_lds[SLOT][0] + ((16 * tid) ^ ((tid >> 7) << 6))) = SW;       \
    __syncthreads(); /* the phase's single barrier */                         \
    float4 xv_[16];                                                           \
    if (wv < 2) { /* issue x(t+1); lands under MFMA/publish below */          \
      const int tt_ = ((t) + 1 < T_STEPS) ? ((t) + 1) : (t);                  \
      const float* xb_ = x + ((size_t)(2 * (G) + (ln & 1)) * T_STEPS          \
                              + (size_t)tt_) * IN_SZ + ((ln >> 4) & 3) * 8;   \
      _Pragma("unroll")                                                       \
      for (int ch = 0; ch < 8; ++ch) {                                        \
        xv_[2 * ch]     = *(const float4*)(xb_ + ch * 32);                    \
        xv_[2 * ch + 1] = *(const float4*)(xb_ + ch * 32 + 4);                \
      }                                                                       \
    }                                                                         \
    { /* pre-issue the next sweep (other stream / next step) */               \
      const u32* np_ = pbuf + (size_t)(NB) * PB_WORDS                         \
                       + (size_t)(NG) * 1024 + 4 * tid;                       \
      asm volatile("global_load_dwordx4 %0, %1, off sc0 sc1"                  \
                   : "=v"(SWN) : "v"(np_) : "memory");                        \
    }                                                                         \
    f32x4 acc_ = {0.f, 0.f, 0.f, 0.f};                                        \
    if (wv <= 2) {                                                            \
      const int beff_ = ln & 1;                                               \
      const int g16_ = ((ln >> 4) & 3) * 16;                                  \
      const char* rb_ = &r_lds[SLOT][0] + beff_ * 2048;                       \
      f32x4 a0_ = {0.f, 0.f, 0.f, 0.f}, a1_ = {0.f, 0.f, 0.f, 0.f};           \
      _Pragma("unroll")                                                       \
      for (int st_ = 0; st_ < 32; st_ += 2) {                                 \
        const s16x8 b0_ =                                                     \
            *(const s16x8*)(rb_ + ((st_ * 64 + g16_) ^ (beff_ << 6)));        \
        const s16x8 b1_ =                                                     \
            *(const s16x8*)(rb_ + (((st_ + 1) * 64 + g16_) ^ (beff_ << 6)));  \
        a0_ = __builtin_amdgcn_mfma_f32_16x16x32_bf16(wfrag[st_], b0_, a0_,   \
                                                      0, 0, 0);               \
        a1_ = __builtin_amdgcn_mfma_f32_16x16x32_bf16(wfrag[st_ + 1], b1_,    \
                                                      a1_, 0, 0, 0);          \
      }                                                                       \
      acc_ = a0_ + a1_;                                                       \
    }                                                                         \
    f32x4 wm_ = {0.f, 0.f, 0.f, 0.f};                                         \
    if (wv < 2) {                                                             \
      _Pragma("unroll")                                                       \
      for (int ch = 0; ch < 8; ++ch)                                          \
        wm_ = __builtin_amdgcn_mfma_f32_16x16x32_bf16(                        \
            wifrag[ch], *(const s16x8*)&XF[ch], wm_, 0, 0, 0);                \
    }                                                                         \
    if (wv < 2 && (ln & 14) == 0) {                                           \
      const int b_ = ln & 1, g4_ = ln >> 4;                                   \
      const u32 ptag_ = (((u32)(t)) >> 1) & 1u;                               \
      const float I0_ = fmaf(0.2f, acc_[0] + wm_[0], 0.8f * IST[0]);          \
      const float I1_ = fmaf(0.2f, acc_[1] + wm_[1], 0.8f * IST[1]);          \
      const float I2_ = fmaf(0.2f, acc_[2] + wm_[2], 0.8f * IST[2]);          \
      const float I3_ = fmaf(0.2f, acc_[3] + wm_[3], 0.8f * IST[3]);          \
      IST[0] = I0_; IST[1] = I1_; IST[2] = I2_; IST[3] = I3_;                 \
      RL[0] = fmaf(0.1f, tanh_fast(I0_), 0.9f * RL[0]);                       \
      RL[1] = fmaf(0.1f, tanh_fast(I1_), 0.9f * RL[1]);                       \
      RL[2] = fmaf(0.1f, tanh_fast(I2_), 0.9f * RL[2]);                       \
      RL[3] = fmaf(0.1f, tanh_fast(I3_), 0.9f * RL[3]);                       \
      u32x2 pk_;                                                              \
      pk_[0] = (((bf16r(RL[1]) << 16) | (bf16r(RL[0]) & 0xFFFFu)) & ~1u) |    \
               ptag_;                                                         \
      pk_[1] = (((bf16r(RL[3]) << 16) | (bf16r(RL[2]) & 0xFFFFu)) & ~1u) |    \
               ptag_;                                                         \
      u32* pw_ = pbuf + (size_t)((t) & 1) * PB_WORDS + (size_t)(G) * 1024 +   \
                 b_ * 512 + jb * 16 + wv * 8 + g4_ * 2;                       \
      asm volatile("global_store_dwordx2 %0, %1, off sc0 sc1"                 \
                   :: "v"(pw_), "v"(pk_) : "memory");                         \
    }                                                                         \
    if (wv == 2 && ln < 2 && (t) > 0) {                                       \
      float4 o_;                                                              \
      o_.x = acc_[0]; o_.y = acc_[1]; o_.z = acc_[2]; o_.w = acc_[3];         \
      *(float4*)(out + ((size_t)(2 * (G) + ln) * T_STEPS +                    \
                        (size_t)((t) - 1)) * OUT_SZ + jb * 4) = o_;           \
    }                                                                         \
    if (wv < 2) { /* convert x(t+1) -> XF (loads have landed by now) */       \
      _Pragma("unroll")                                                       \
      for (int ch = 0; ch < 8; ++ch) {                                        \
        u32x4 u_;                                                             \
        u_[0] = __builtin_amdgcn_perm(__float_as_uint(xv_[2 * ch].y),         \
                                      __float_as_uint(xv_[2 * ch].x),         \
                                      0x07060302u);                           \
        u_[1] = __builtin_amdgcn_perm(__float_as_uint(xv_[2 * ch].w),         \
                                      __float_as_uint(xv_[2 * ch].z),         \
                                      0x07060302u);                           \
        u_[2] = __builtin_amdgcn_perm(__float_as_uint(xv_[2 * ch + 1].y),     \
                                      __float_as_uint(xv_[2 * ch + 1].x),     \
                                      0x07060302u);                           \
        u_[3] = __builtin_amdgcn_perm(__float_as_uint(xv_[2 * ch + 1].w),     \
                                      __float_as_uint(xv_[2 * ch + 1].z),     \
                                      0x07060302u);                           \
        XF[ch] = u_;                                                          \
      }                                                                       \
    }                                                                         \
  } while (0)

__global__ void __launch_bounds__(WGS, 1)
nrnn_main(const float* __restrict__ x, const float* __restrict__ Win,
          const float* __restrict__ Wrec, const float* __restrict__ Wout,
          float* __restrict__ out, float* __restrict__ ws) {
  const int tid = (int)threadIdx.x;
  const int wv  = tid >> 6;   // wave: 0,1 = Wrec+Win MFMA; 2 = Wout MFMA; 3 = aux
  const int ln  = tid & 63;
  const int P   = (int)blockIdx.x & 7;
  const int jb  = (int)blockIdx.x >> 3;  // h-slice [32jb, 32jb+32)
  const int gA = P, gB = P + 8;          // group g = batches {2g, 2g+1}

  u32* pbuf = (u32*)ws;
  __shared__ __align__(16) char r_lds[2][4096];  // per-stream bf16 r, swizzled

  // ---- Wrec/Wout A-fragments (static bf16; SHARED by both streams) ----
  s16x8 wfrag[32];
  {
    const int g = (ln >> 4) & 3;
    const float* wp;
    if (wv < 2)       wp = Wrec + (size_t)(jb * 32 + wv * 16 + (ln & 15)) * H_SZ;
    else if (wv == 2) wp = Wout + (size_t)(jb * 4 + (ln & 3)) * H_SZ;
    else              wp = Wrec;  // wave 3: content unused
    #pragma unroll
    for (int st = 0; st < 32; ++st) {
      const int k0 = st * 32 + g * 8;
      const float4 c0 = *(const float4*)(wp + k0);
      const float4 c1 = *(const float4*)(wp + k0 + 4);
      s16x8 w;
      w[0] = (short)bf16r(c0.x); w[1] = (short)bf16r(c0.y);
      w[2] = (short)bf16r(c0.z); w[3] = (short)bf16r(c0.w);
      w[4] = (short)bf16r(c1.x); w[5] = (short)bf16r(c1.y);
      w[6] = (short)bf16r(c1.z); w[7] = (short)bf16r(c1.w);
      wfrag[st] = w;
    }
  }

  // ---- Win A-fragments (waves 0,1) ----
  s16x8 wifrag[8];
  if (wv < 2) {
    const float* wp = Win + (size_t)(jb * 32 + wv * 16 + (ln & 15)) * IN_SZ
                      + ((ln >> 4) & 3) * 8;
    #pragma unroll
    for (int ch = 0; ch < 8; ++ch) {
      const float4 c0 = *(const float4*)(wp + ch * 32);
      const float4 c1 = *(const float4*)(wp + ch * 32 + 4);
      s16x8 w;
      w[0] = (short)bf16r(c0.x); w[1] = (short)bf16r(c0.y);
      w[2] = (short)bf16r(c0.z); w[3] = (short)bf16r(c0.w);
      w[4] = (short)bf16r(c1.x); w[5] = (short)bf16r(c1.y);
      w[6] = (short)bf16r(c1.z); w[7] = (short)bf16r(c1.w);
      wifrag[ch] = w;
    }
  } else {
    const s16x8 z = {0, 0, 0, 0, 0, 0, 0, 0};
    #pragma unroll
    for (int ch = 0; ch < 8; ++ch) wifrag[ch] = z;
  }

  // ---- per-stream persistent state ----
  float IstA[4] = {0.f, 0.f, 0.f, 0.f}, rlA[4] = {0.f, 0.f, 0.f, 0.f};
  float IstB[4] = {0.f, 0.f, 0.f, 0.f}, rlB[4] = {0.f, 0.f, 0.f, 0.f};
  u32x4 xfA[8], xfB[8];

  // ---- prologue: x(0) for both streams; pre-issue sweep A(0) (buffer 1) ----
  {
    float4 xv0[16];
    #pragma unroll
    for (int S = 0; S < 2; ++S) {
      const int G = S ? gB : gA;
      if (wv < 2) {
        const float* xb = x + ((size_t)(2 * G + (ln & 1)) * T_STEPS) * IN_SZ
                          + ((ln >> 4) & 3) * 8;
        #pragma unroll
        for (int ch = 0; ch < 8; ++ch) {
          xv0[2 * ch]     = *(const float4*)(xb + ch * 32);
          xv0[2 * ch + 1] = *(const float4*)(xb + ch * 32 + 4);
        }
        #pragma unroll
        for (int ch = 0; ch < 8; ++ch) {
          u32x4 u;
          u[0] = __builtin_amdgcn_perm(__float_as_uint(xv0[2 * ch].y),
                                       __float_as_uint(xv0[2 * ch].x), 0x07060302u);
          u[1] = __builtin_amdgcn_perm(__float_as_uint(xv0[2 * ch].w),
                                       __float_as_uint(xv0[2 * ch].z), 0x07060302u);
          u[2] = __builtin_amdgcn_perm(__float_as_uint(xv0[2 * ch + 1].y),
                                       __float_as_uint(xv0[2 * ch + 1].x), 0x07060302u);
          u[3] = __builtin_amdgcn_perm(__float_as_uint(xv0[2 * ch + 1].w),
                                       __float_as_uint(xv0[2 * ch + 1].z), 0x07060302u);
          if (S) xfB[ch] = u; else xfA[ch] = u;
        }
      }
    }
  }
  u32x4 swA, swB;
  {
    const u32* sp = pbuf + (size_t)PB_WORDS + (size_t)gA * 1024 + 4 * tid;
    asm volatile("global_load_dwordx4 %0, %1, off sc0 sc1"
                 : "=v"(swA) : "v"(sp) : "memory");
  }

  for (int t = 0; t < T_STEPS; ++t) {
    // phase A: stream gA/slot 0; pre-issues sweep B(t) into buffer (t+1)&1
    PHASE(gA, 0, t, swA, swB, gB, (t + 1) & 1, IstA, rlA, xfA);
    // phase B: stream gB/slot 1; pre-issues sweep A(t+1) into buffer t&1
    PHASE(gB, 1, t, swB, swA, gA, t & 1, IstB, rlB, xfB);
  }

  // ---- epilogue: out(T-1) for both streams (r published at T-1 -> buffer 1) ----
  const u32 etagF = (((u32)(T_STEPS - 1)) >> 1) & 1u;
  {
    // stream A (sweep pre-issued by phase B(T-1))
    const u32* sp = pbuf + (size_t)PB_WORDS + (size_t)gA * 1024 + 4 * tid;
    asm volatile("s_waitcnt vmcnt(0)" : "+v"(swA) :: "memory");
    for (;;) {
      const u32 bad = (swA[0] ^ etagF) | (swA[1] ^ etagF) |
                      (swA[2] ^ etagF) | (swA[3] ^ etagF);
      if (!__any(bad & 1u)) break;
      asm volatile("global_load_dwordx4 %0, %1, off sc0 sc1\n\t"
                   "s_waitcnt vmcnt(0)"
                   : "=&v"(swA) : "v"(sp) : "memory");
    }
    *(u32x4*)(&r_lds[0][0] + ((16 * tid) ^ ((tid >> 7) << 6))) = swA;
    __syncthreads();
    if (wv == 2) {
      const int beff = ln & 1;
      const int g16 = ((ln >> 4) & 3) * 16;
      const char* rb = &r_lds[0][0] + beff * 2048;
      f32x4 acc = {0.f, 0.f, 0.f, 0.f};
      #pragma unroll
      for (int st = 0; st < 32; ++st) {
        const s16x8 bf = *(const s16x8*)(rb + ((st * 64 + g16) ^ (beff << 6)));
        acc = __builtin_amdgcn_mfma_f32_16x16x32_bf16(wfrag[st], bf, acc, 0, 0, 0);
      }
      if (ln < 2) {
        float4 o; o.x = acc[0]; o.y = acc[1]; o.z = acc[2]; o.w = acc[3];
        *(float4*)(out + ((size_t)(2 * gA + ln) * T_STEPS +
                          (size_t)(T_STEPS - 1)) * OUT_SZ + jb * 4) = o;
      }
    }
    // stream B (fresh sweep)
    const u32* spB = pbuf + (size_t)PB_WORDS + (size_t)gB * 1024 + 4 * tid;
    asm volatile("global_load_dwordx4 %0, %1, off sc0 sc1\n\t"
                 "s_waitcnt vmcnt(0)"
                 : "=&v"(swB) : "v"(spB) : "memory");
    for (;;) {
      const u32 bad = (swB[0] ^ etagF) | (swB[1] ^ etagF) |
                      (swB[2] ^ etagF) | (swB[3] ^ etagF);
      if (!__any(bad & 1u)) break;
      asm volatile("global_load_dwordx4 %0, %1, off sc0 sc1\n\t"
                   "s_waitcnt vmcnt(0)"
                   : "=&v"(swB) : "v"(spB) : "memory");
    }
    *(u32x4*)(&r_lds[1][0] + ((16 * tid) ^ ((tid >> 7) << 6))) = swB;
    __syncthreads();
    if (wv == 2) {
      const int beff = ln & 1;
      const int g16 = ((ln >> 4) & 3) * 16;
      const char* rb = &r_lds[1][0] + beff * 2048;
      f32x4 acc = {0.f, 0.f, 0.f, 0.f};
      #pragma unroll
      for (int st = 0; st < 32; ++st) {
        const s16x8 bf = *(const s16x8*)(rb + ((st * 64 + g16) ^ (beff << 6)));
        acc = __builtin_amdgcn_mfma_f32_16x16x32_bf16(wfrag[st], bf, acc, 0, 0, 0);
      }
      if (ln < 2) {
        float4 o; o.x = acc[0]; o.y = acc[1]; o.z = acc[2]; o.w = acc[3];
        *(float4*)(out + ((size_t)(2 * gB + ln) * T_STEPS +
                          (size_t)(T_STEPS - 1)) * OUT_SZ + jb * 4) = o;
      }
    }
  }
}

extern "C" void kernel_launch(void* const* d_in, const int* in_sizes, int n_in,
                              void* d_out, int out_size, void* d_ws, size_t ws_size,
                              hipStream_t stream) {
  const float* xp    = (const float*)d_in[0];
  const float* winp  = (const float*)d_in[1];
  const float* wrecp = (const float*)d_in[2];
  const float* woutp = (const float*)d_in[3];
  float* outp = (float*)d_out;
  float* wsp  = (float*)d_ws;

  // re-init packed r buffers to tag=1 / value~0 every call (graph-replay safe)
  nrnn_init_ws<<<(WS_WORDS + 255) / 256, 256, 0, stream>>>((u32*)d_ws);

  nrnn_main<<<dim3(NWG), dim3(WGS), 0, stream>>>(xp, winp, wrecp, woutp, outp, wsp);
}

// Round 15
// 5499.286 us; speedup vs baseline: 1.6866x; 1.6866x over previous
//
#include <hip/hip_runtime.h>
#include <math.h>

// NeuroRNN: I = 0.8 I + 0.2 (Wrec r + Win x_t); r = 0.9 r + 0.1 tanh(I); out = Wout r
// B=32, T=2048, IN=256, H=1024, OUT=128 (all fp32)
//
// R15 = R12 (best passing, 5.51 ms) + RAW BARRIERS ONLY (the safe half of R14):
//  - __syncthreads() forces s_waitcnt vmcnt(0) before s_barrier, serializing the
//    pre-issued sweep + publish ack into every step. Replaced with
//    s_waitcnt lgkmcnt(0) (barrier A only; LDS-write visibility) +
//    __builtin_amdgcn_s_barrier() + sched_barrier(0) fences (m201 pattern).
//  - R14's 3-slot pipeline is REMOVED: it left asm loads in flight across
//    compiler-generated x-loads, corrupting hipcc's vmcnt bookkeeping (the
//    R14 correctness failure). Rule: every asm block ends vmcnt(0); the single
//    pre-issued sweep dangles only across barrier B where no compiler memory
//    ops exist.
// Everything else identical to R12: MFMA compute (Wrec 32x + Win 8x on waves
// 0,1; Wout on wave 2), bf16 tag-in-data exchange over MALL (sc0 sc1),
// fire-and-forget publish, v_perm x-packing.

#define T_STEPS 2048
#define IN_SZ 256
#define H_SZ 1024
#define OUT_SZ 128
#define WGS 256
#define NWG 256
#define PB_WORDS 16384                 // dwords per dbuf half: 32 batch x 512
#define WS_WORDS (2 * PB_WORDS)

typedef unsigned int u32;
typedef u32 u32x2 __attribute__((ext_vector_type(2)));
typedef u32 u32x4 __attribute__((ext_vector_type(4)));
typedef float f32x4 __attribute__((ext_vector_type(4)));
typedef short s16x8 __attribute__((ext_vector_type(8)));

// init: tag bit = 1 (expected tag for "step -1"), bf16 halves ~= 0
__global__ void nrnn_init_ws(u32* __restrict__ ws) {
  const int i = blockIdx.x * blockDim.x + threadIdx.x;
  if (i < WS_WORDS) ws[i] = 0x00000001u;
}

__device__ __forceinline__ u32 bf16r(float v) {  // round-to-nearest-even bf16
  const u32 b = __float_as_uint(v);
  return (b + 0x7FFFu + ((b >> 16) & 1u)) >> 16;
}
__device__ __forceinline__ float tanh_fast(float v) {
  const float cx = fminf(fmaxf(v, -15.f), 15.f);
  const float e = __expf(2.f * cx);
  return (e - 1.f) * __builtin_amdgcn_rcpf(e + 1.f);
}

__global__ void __launch_bounds__(WGS, 1)
nrnn_main(const float* __restrict__ x, const float* __restrict__ Win,
          const float* __restrict__ Wrec, const float* __restrict__ Wout,
          float* __restrict__ out, float* __restrict__ ws) {
  const int tid = (int)threadIdx.x;
  const int wv  = tid >> 6;   // wave: 0,1 = Wrec+Win MFMA; 2 = Wout MFMA; 3 = aux
  const int ln  = tid & 63;   // lane in wave
  const int bg  = (int)blockIdx.x & 7;   // batch group (batches [4bg,4bg+4))
  const int jb  = (int)blockIdx.x >> 3;  // h-slice [32jb, 32jb+32)
  const int b0  = bg * 4;

  u32* pbuf = (u32*)ws;
  __shared__ __align__(16) char r_lds[8192];  // bf16 r [4 batch][1024 k], swizzled

  // ---- Wrec/Wout A-fragments -> VGPRs (static bf16, R9-proven layout) ----
  s16x8 wfrag[32];
  {
    const int g = (ln >> 4) & 3;
    const float* wp;
    if (wv < 2)       wp = Wrec + (size_t)(jb * 32 + wv * 16 + (ln & 15)) * H_SZ;
    else if (wv == 2) wp = Wout + (size_t)(jb * 4 + (ln & 3)) * H_SZ;
    else              wp = Wrec;  // wave 3: content unused
    #pragma unroll
    for (int st = 0; st < 32; ++st) {
      const int k0 = st * 32 + g * 8;
      const float4 c0 = *(const float4*)(wp + k0);
      const float4 c1 = *(const float4*)(wp + k0 + 4);
      s16x8 w;
      w[0] = (short)bf16r(c0.x); w[1] = (short)bf16r(c0.y);
      w[2] = (short)bf16r(c0.z); w[3] = (short)bf16r(c0.w);
      w[4] = (short)bf16r(c1.x); w[5] = (short)bf16r(c1.y);
      w[6] = (short)bf16r(c1.z); w[7] = (short)bf16r(c1.w);
      wfrag[st] = w;
    }
  }

  // ---- Win A-fragments (waves 0,1; same rows as their Wrec rows) ----
  s16x8 wifrag[8];
  if (wv < 2) {
    const float* wp = Win + (size_t)(jb * 32 + wv * 16 + (ln & 15)) * IN_SZ
                      + ((ln >> 4) & 3) * 8;
    #pragma unroll
    for (int ch = 0; ch < 8; ++ch) {
      const float4 c0 = *(const float4*)(wp + ch * 32);
      const float4 c1 = *(const float4*)(wp + ch * 32 + 4);
      s16x8 w;
      w[0] = (short)bf16r(c0.x); w[1] = (short)bf16r(c0.y);
      w[2] = (short)bf16r(c0.z); w[3] = (short)bf16r(c0.w);
      w[4] = (short)bf16r(c1.x); w[5] = (short)bf16r(c1.y);
      w[6] = (short)bf16r(c1.z); w[7] = (short)bf16r(c1.w);
      wifrag[ch] = w;
    }
  } else {
    const s16x8 z = {0, 0, 0, 0, 0, 0, 0, 0};
    #pragma unroll
    for (int ch = 0; ch < 8; ++ch) wifrag[ch] = z;
  }

  // x loader (B-frag slots: col=batch=ln&3, k=(ln>>4)*8 within each 32-chunk)
  auto ldx_issue = [&](int tt, float4 (&xv)[16]) {
    if (wv < 2) {
      const float* xb = x + ((size_t)(b0 + (ln & 3)) * T_STEPS + (size_t)tt) * IN_SZ
                        + ((ln >> 4) & 3) * 8;
      #pragma unroll
      for (int ch = 0; ch < 8; ++ch) {
        xv[2 * ch]     = *(const float4*)(xb + ch * 32);
        xv[2 * ch + 1] = *(const float4*)(xb + ch * 32 + 4);
      }
    }
  };
  // fp32 -> packed bf16 (RTZ via v_perm: dst = hi16(a)<<16 | hi16(b))
  auto cvt = [&](const float4 (&xv)[16], u32x4 (&xf)[8]) {
    if (wv < 2) {
      #pragma unroll
      for (int ch = 0; ch < 8; ++ch) {
        u32x4 u;
        u[0] = __builtin_amdgcn_perm(__float_as_uint(xv[2 * ch].y),
                                     __float_as_uint(xv[2 * ch].x), 0x07060302u);
        u[1] = __builtin_amdgcn_perm(__float_as_uint(xv[2 * ch].w),
                                     __float_as_uint(xv[2 * ch].z), 0x07060302u);
        u[2] = __builtin_amdgcn_perm(__float_as_uint(xv[2 * ch + 1].y),
                                     __float_as_uint(xv[2 * ch + 1].x), 0x07060302u);
        u[3] = __builtin_amdgcn_perm(__float_as_uint(xv[2 * ch + 1].w),
                                     __float_as_uint(xv[2 * ch + 1].z), 0x07060302u);
        xf[ch] = u;
      }
    }
  };

  // ---- persistent state (publishing lanes of waves 0,1) ----
  float Ist[4] = {0.f, 0.f, 0.f, 0.f};
  float rloc[4] = {0.f, 0.f, 0.f, 0.f};

  // ---- prologue: x(0) -> xf; pre-issue sweep for t=0 (buffer 1, tag 1) ----
  u32x4 xf[8];
  {
    float4 xv0[16];
    ldx_issue(0, xv0);
    cvt(xv0, xf);
  }
  u32x4 swa, swb;
  {
    const u32* sp0 = pbuf + (size_t)PB_WORDS + (size_t)bg * 2048 + 4 * tid;
    asm volatile("global_load_dwordx4 %0, %2, off sc0 sc1\n\t"
                 "global_load_dwordx4 %1, %3, off sc0 sc1"
                 : "=v"(swa), "=v"(swb) : "v"(sp0), "v"(sp0 + 1024) : "memory");
  }

  for (int t = 0; t < T_STEPS; ++t) {
    // ---- finish pre-issued sweep; retry until all tags match (R12 poll) ----
    const u32 etag = (((u32)(t - 1)) >> 1) & 1u;
    const u32* sp0 = pbuf + (size_t)((t + 1) & 1) * PB_WORDS + (size_t)bg * 2048 + 4 * tid;
    asm volatile("s_waitcnt vmcnt(0)" : "+v"(swa), "+v"(swb) :: "memory");
    for (;;) {
      u32 bad = 0;
      #pragma unroll
      for (int i = 0; i < 4; ++i) { bad |= swa[i] ^ etag; bad |= swb[i] ^ etag; }
      if (!__any(bad & 1u)) break;
      asm volatile("global_load_dwordx4 %0, %2, off sc0 sc1\n\t"
                   "global_load_dwordx4 %1, %3, off sc0 sc1\n\t"
                   "s_waitcnt vmcnt(0)"
                   : "=&v"(swa), "=&v"(swb) : "v"(sp0), "v"(sp0 + 1024) : "memory");
    }
    // ---- stage to swizzled LDS (R9-proven, conflict-free) ----
    {
      const int bi0 = tid >> 7, bi1 = 2 + bi0;
      *(u32x4*)(r_lds + ((16 * tid) ^ ((bi0 & 3) << 4) ^ ((bi0 & 1) << 6))) = swa;
      *(u32x4*)(r_lds + ((4096 + 16 * tid) ^ ((bi1 & 3) << 4) ^ ((bi1 & 1) << 6))) = swb;
    }

    // ---- barrier A (raw): LDS-write visibility only, NO vmcnt drain ----
    asm volatile("s_waitcnt lgkmcnt(0)" ::: "memory");
    __builtin_amdgcn_s_barrier();
    __builtin_amdgcn_sched_barrier(0);

    // ---- issue x(t+1) loads (latency hides under MFMA/publish below) ----
    float4 xv[16];
    ldx_issue((t + 1 < T_STEPS) ? t + 1 : t, xv);

    // ---- Wrec / Wout MFMA over K=1024, dual accumulator chains ----
    f32x4 acc = {0.f, 0.f, 0.f, 0.f};
    if (wv <= 2) {
      const int beff = ln & 3;
      const int g16 = ((ln >> 4) & 3) * 16;
      const int bswz = ((beff & 3) << 4) | ((beff & 1) << 6);
      const char* rb = r_lds + beff * 2048;
      f32x4 a0 = {0.f, 0.f, 0.f, 0.f}, a1 = {0.f, 0.f, 0.f, 0.f};
      #pragma unroll
      for (int st = 0; st < 32; st += 2) {
        const s16x8 bfa = *(const s16x8*)(rb + ((st * 64 + g16) ^ bswz));
        const s16x8 bfb = *(const s16x8*)(rb + (((st + 1) * 64 + g16) ^ bswz));
        a0 = __builtin_amdgcn_mfma_f32_16x16x32_bf16(wfrag[st], bfa, a0, 0, 0, 0);
        a1 = __builtin_amdgcn_mfma_f32_16x16x32_bf16(wfrag[st + 1], bfb, a1, 0, 0, 0);
      }
      acc = a0 + a1;
    }

    // ---- Win*x via MFMA (waves 0,1; same C layout as acc) ----
    f32x4 wm = {0.f, 0.f, 0.f, 0.f};
    if (wv < 2) {
      #pragma unroll
      for (int ch = 0; ch < 8; ++ch)
        wm = __builtin_amdgcn_mfma_f32_16x16x32_bf16(wifrag[ch],
                                                     *(const s16x8*)&xf[ch], wm, 0, 0, 0);
    }

    // ---- I update; tanh; tagged bf16 publish (fire-and-forget dwordx2) ----
    if (wv < 2 && (ln & 12) == 0) {
      const int b = ln & 3, g4 = ln >> 4;
      const u32 ptag = (((u32)t) >> 1) & 1u;
      const float I0 = fmaf(0.2f, acc[0] + wm[0], 0.8f * Ist[0]);
      const float I1 = fmaf(0.2f, acc[1] + wm[1], 0.8f * Ist[1]);
      const float I2 = fmaf(0.2f, acc[2] + wm[2], 0.8f * Ist[2]);
      const float I3 = fmaf(0.2f, acc[3] + wm[3], 0.8f * Ist[3]);
      Ist[0] = I0; Ist[1] = I1; Ist[2] = I2; Ist[3] = I3;
      rloc[0] = fmaf(0.1f, tanh_fast(I0), 0.9f * rloc[0]);
      rloc[1] = fmaf(0.1f, tanh_fast(I1), 0.9f * rloc[1]);
      rloc[2] = fmaf(0.1f, tanh_fast(I2), 0.9f * rloc[2]);
      rloc[3] = fmaf(0.1f, tanh_fast(I3), 0.9f * rloc[3]);
      u32x2 pk;
      pk[0] = (((bf16r(rloc[1]) << 16) | (bf16r(rloc[0]) & 0xFFFFu)) & ~1u) | ptag;
      pk[1] = (((bf16r(rloc[3]) << 16) | (bf16r(rloc[2]) & 0xFFFFu)) & ~1u) | ptag;
      u32* pw = pbuf + (size_t)(t & 1) * PB_WORDS + (size_t)(b0 + b) * 512
                + jb * 16 + wv * 8 + g4 * 2;
      asm volatile("global_store_dwordx2 %0, %1, off sc0 sc1"
                   :: "v"(pw), "v"(pk) : "memory");
    }

    // ---- wave 2: out_{t-1} = Wout r_{t-1} (one float4 store) ----
    if (wv == 2 && ln < 4 && t > 0) {
      float4 o; o.x = acc[0]; o.y = acc[1]; o.z = acc[2]; o.w = acc[3];
      *(float4*)(out + ((size_t)(b0 + ln) * T_STEPS + (size_t)(t - 1)) * OUT_SZ
                 + jb * 4) = o;
    }

    // ---- convert x(t+1) -> xf (x loads have landed under the work above) ----
    cvt(xv, xf);

    // ---- pre-issue sweep for t+1 (buffer t&1); dangles ONLY across barrier B
    //      (no compiler memory ops until next poll's vmcnt(0)) ----
    {
      const u32* np0 = pbuf + (size_t)(t & 1) * PB_WORDS + (size_t)bg * 2048 + 4 * tid;
      asm volatile("global_load_dwordx4 %0, %2, off sc0 sc1\n\t"
                   "global_load_dwordx4 %1, %3, off sc0 sc1"
                   : "=v"(swa), "=v"(swb) : "v"(np0), "v"(np0 + 1024) : "memory");
    }

    // ---- barrier B (raw): read-before-overwrite ordering only, NO drains ----
    __builtin_amdgcn_sched_barrier(0);
    __builtin_amdgcn_s_barrier();
    __builtin_amdgcn_sched_barrier(0);
  }

  // ---- epilogue: out(T-1); pre-issued sweep targets buffer 1, etag 1 ----
  {
    const u32 etag = (((u32)(T_STEPS - 1)) >> 1) & 1u;
    const u32* sp0 = pbuf + (size_t)PB_WORDS + (size_t)bg * 2048 + 4 * tid;
    asm volatile("s_waitcnt vmcnt(0)" : "+v"(swa), "+v"(swb) :: "memory");
    for (;;) {
      u32 bad = 0;
      #pragma unroll
      for (int i = 0; i < 4; ++i) { bad |= swa[i] ^ etag; bad |= swb[i] ^ etag; }
      if (!__any(bad & 1u)) break;
      asm volatile("global_load_dwordx4 %0, %2, off sc0 sc1\n\t"
                   "global_load_dwordx4 %1, %3, off sc0 sc1\n\t"
                   "s_waitcnt vmcnt(0)"
                   : "=&v"(swa), "=&v"(swb) : "v"(sp0), "v"(sp0 + 1024) : "memory");
    }
    const int bi0 = tid >> 7, bi1 = 2 + bi0;
    *(u32x4*)(r_lds + ((16 * tid) ^ ((bi0 & 3) << 4) ^ ((bi0 & 1) << 6))) = swa;
    *(u32x4*)(r_lds + ((4096 + 16 * tid) ^ ((bi1 & 3) << 4) ^ ((bi1 & 1) << 6))) = swb;
  }
  __syncthreads();
  if (wv == 2) {
    const int beff = ln & 3;
    const int g16 = ((ln >> 4) & 3) * 16;
    const int bswz = ((beff & 3) << 4) | ((beff & 1) << 6);
    const char* rb = r_lds + beff * 2048;
    f32x4 acc = {0.f, 0.f, 0.f, 0.f};
    #pragma unroll
    for (int st = 0; st < 32; ++st) {
      const s16x8 bf = *(const s16x8*)(rb + ((st * 64 + g16) ^ bswz));
      acc = __builtin_amdgcn_mfma_f32_16x16x32_bf16(wfrag[st], bf, acc, 0, 0, 0);
    }
    if (ln < 4) {
      float4 o; o.x = acc[0]; o.y = acc[1]; o.z = acc[2]; o.w = acc[3];
      *(float4*)(out + ((size_t)(b0 + ln) * T_STEPS + (size_t)(T_STEPS - 1)) * OUT_SZ
                 + jb * 4) = o;
    }
  }
}

extern "C" void kernel_launch(void* const* d_in, const int* in_sizes, int n_in,
                              void* d_out, int out_size, void* d_ws, size_t ws_size,
                              hipStream_t stream) {
  const float* xp    = (const float*)d_in[0];
  const float* winp  = (const float*)d_in[1];
  const float* wrecp = (const float*)d_in[2];
  const float* woutp = (const float*)d_in[3];
  float* outp = (float*)d_out;
  float* wsp  = (float*)d_ws;

  // re-init packed r buffers to tag=1 / value~0 every call (graph-replay safe)
  nrnn_init_ws<<<(WS_WORDS + 255) / 256, 256, 0, stream>>>((u32*)d_ws);

  nrnn_main<<<dim3(NWG), dim3(WGS), 0, stream>>>(xp, winp, wrecp, woutp, outp, wsp);
}